// Round 13
// baseline (1427.161 us; speedup 1.0000x reference)
//
#include <hip/hip_runtime.h>
#include <math.h>

// Problem constants (E,B,M,C) = (64, 512, 128, 128), sigma=0.5, eps=1e-6
#define MM   128
#define CC   128
#define EE   64
#define BB   512
#define LDT  132          // padded row stride for At in LDS (measured conflict-free r4-r12)
#define SIG2 0.25f
#define SIG4 0.0625f
#define EPSV 1e-6f

// LDS layout (floats): At[128][132] + 9 vectors of 128 + 32 scalars = 72,320 B
// -> TWO blocks/CU (2 x 72.3 KB <= 160 KB LDS; 8 waves x <=256 VGPR = 2048 = pool).
#define AT_OFF   0
#define VEC_BASE (128*LDT)
#define VEC(i)   (VEC_BASE + (i)*128)
// vec: 0 vz, 1 vaz, 2 vw0(w), 3 vt2(z->dl), 4 vuw, 5 g1-bank0, 6 g1-bank1, 7 g2-bank0, 8 g2-bank1
#define SC_OFF   (VEC_BASE + 9*128)
// scal: [0..7]=bank0, [8..15]=bank1 ([+0]=sig [+1]=d2 [+2]=s_uwg2 [+3]=s_vg1/SIG4 [+4]=s_uwg1/SIG2)
//       [16..19]=epilogue wave sums, [30]=GJ pivot
#define SMEM_FLOATS (SC_OFF + 32)
#define SMEM_BYTES  (SMEM_FLOATS * 4)    // 72,320 B

// ---------------------------------------------------------------------------
// 256 threads = 4 waves: w = t>>6, l = t&63
//   r = 64*(w&1)+l (row owned), q = w>>1 (0..1), cb = 64*q (column chunk)
// REGISTERS: Areg[64] + Ureg[64] + Greg[64] = 192 state (~230 live).
// LDS: At + step vectors only (72.3 KB -> 2 blocks/CU).
// OCCUPANCY DESIGN (r1/r9/m69 evidence): two 4-wave blocks co-reside at
// <=256 VGPR (r1 measured 23.5% occ at 73.3 KB); 8-wave blocks at 128 VGPR
// do NOT (r9: 16x128=2048 exact-fit fails). Block A's barrier bubbles are
// filled by block B's matvecs — attacks the ~4x latency-serialization gap.
// REGISTER LAW (r1-r12): budget = 256 / max_waves_per_eu -> (1,1) = 256.
// 3-phase schedule (dependency-depth minimum), deferred Ginv update,
// v = SIG2*w identity — all carried from the passing r12 kernel.
// ---------------------------------------------------------------------------
#define KATTR __attribute__((amdgpu_flat_work_group_size(256, 256), amdgpu_waves_per_eu(1, 1)))

// In-place Gauss-Jordan inverse of (A A^T + SIG2*I), 256 threads.
// A staged row-major in T=[128][LDT]; destroys T; leaves Ginv in T.
// Map: rg = t>>1, cq = t&1, ccb = 64*cq.
__device__ __forceinline__ void ginv_inplace(float* sm, const int t) {
    float* T   = sm + AT_OFF;
    float* piv = sm + SC_OFF + 30;
    const int rg = t >> 1, cq = t & 1, ccb = cq << 6;
    float Gacc[64];
    #pragma unroll
    for (int j = 0; j < 64; ++j) Gacc[j] = 0.f;
    #pragma unroll 1
    for (int cc = 0; cc < 32; ++cc) {
        const float4 ar = *(const float4*)&T[rg*LDT + 4*cc];
        #pragma unroll
        for (int j = 0; j < 64; ++j) {
            const float4 br = *(const float4*)&T[(ccb + j)*LDT + 4*cc];
            Gacc[j] += ar.x*br.x + ar.y*br.y + ar.z*br.z + ar.w*br.w;
        }
    }
    #pragma unroll
    for (int j = 0; j < 64; ++j)
        if (ccb + j == rg) Gacc[j] += SIG2;
    __syncthreads();
    #pragma unroll
    for (int j4 = 0; j4 < 16; ++j4) {
        float4 v; v.x = Gacc[4*j4]; v.y = Gacc[4*j4+1]; v.z = Gacc[4*j4+2]; v.w = Gacc[4*j4+3];
        *(float4*)&T[rg*LDT + ccb + 4*j4] = v;
    }
    #pragma unroll 1
    for (int k = 0; k < 128; ++k) {
        const int kq = k >> 6;
        __syncthreads();
        if (rg == k && cq == kq) piv[0] = 1.0f / T[k*LDT + k];
        __syncthreads();
        if (rg == k) {
            const float pinv = piv[0];
            #pragma unroll
            for (int j4 = 0; j4 < 16; ++j4) {
                float4 g = *(float4*)&T[k*LDT + ccb + 4*j4];
                g.x *= pinv; g.y *= pinv; g.z *= pinv; g.w *= pinv;
                *(float4*)&T[k*LDT + ccb + 4*j4] = g;
            }
            if (cq == kq) T[k*LDT + k] = pinv;   // identity-column trick
        }
        __syncthreads();
        const float f = (rg == k) ? 0.f : T[rg*LDT + k];
        __syncthreads();
        if (rg != k) {
            #pragma unroll
            for (int j4 = 0; j4 < 16; ++j4) {
                float4 own = *(float4*)&T[rg*LDT + ccb + 4*j4];
                const float4 pv = *(const float4*)&T[k*LDT + ccb + 4*j4];
                own.x -= f*pv.x; own.y -= f*pv.y; own.z -= f*pv.z; own.w -= f*pv.w;
                *(float4*)&T[rg*LDT + ccb + 4*j4] = own;
            }
            if (cq == kq) T[rg*LDT + k] -= f;    // blind gave f - f*pinv; want -f*pinv
        }
    }
    __syncthreads();
}

__global__ KATTR void gpm_setup(const float* __restrict__ mean0,
                                float* __restrict__ ginv0) {
    extern __shared__ float sm[];
    float* T = sm + AT_OFF;
    const int t = threadIdx.x;
    const int rg = t >> 1, cq = t & 1, ccb = cq << 6;
    const float* src = mean0 + rg*CC + ccb;
    #pragma unroll
    for (int j4 = 0; j4 < 16; ++j4)
        *(float4*)&T[rg*LDT + ccb + 4*j4] = *(const float4*)&src[4*j4];
    __syncthreads();
    ginv_inplace(sm, t);
    #pragma unroll
    for (int j4 = 0; j4 < 16; ++j4)
        *(float4*)&ginv0[rg*CC + ccb + 4*j4] = *(const float4*)&T[rg*LDT + ccb + 4*j4];
}

// 3-level shuffle (8-lane groups) then 1-in-8 lanes atomic into a scalar slot
#define SC_ADD(base, slot, val) { float v_ = (val);                           \
    v_ += __shfl_xor(v_, 1, 64); v_ += __shfl_xor(v_, 2, 64);                 \
    v_ += __shfl_xor(v_, 4, 64);                                              \
    if ((l & 7) == 0) atomicAdd(&(base)[slot], v_); }

__global__ KATTR void gpm_main(
        const float* __restrict__ zin, const float* __restrict__ mean0,
        const float* __restrict__ lvar, float* __restrict__ out,
        const float* __restrict__ ginv0, const int use_ws) {
    extern __shared__ float sm[];
    float* At  = sm + AT_OFF;
    float* vz  = sm + VEC(0);
    float* vaz = sm + VEC(1);
    float* vw0 = sm + VEC(2);
    float* vt2 = sm + VEC(3);   // z copy in Pa; dl after Pb
    float* vuw = sm + VEC(4);
    float* scal = sm + SC_OFF;

    const int t = threadIdx.x, b = blockIdx.x;
    const int w = t >> 6, l = t & 63;
    const int r  = ((w & 1) << 6) | l;
    const int q  = w >> 1;
    const int cb = q << 6;

    // zero accumulator vectors VEC(1)..VEC(8) (1024 floats) + scalar slots
    sm[VEC(1) + t] = 0.f;
    sm[VEC(1) + 256 + t] = 0.f;
    sm[VEC(1) + 512 + t] = 0.f;
    sm[VEC(1) + 768 + t] = 0.f;
    if (t < 32) scal[t] = 0.f;
    __syncthreads();
    if (t == 0) { scal[0] = SIG2; scal[8] = SIG2; }   // sig slots of both banks

    const float pvar = expf(lvar[0]) + EPSV;

    float Areg[64], Ureg[64], Greg[64];

    if (use_ws) {
        const float* src = ginv0 + r*CC + cb;
        #pragma unroll
        for (int j4 = 0; j4 < 16; ++j4) {
            const float4 v = *(const float4*)&src[4*j4];
            Greg[4*j4] = v.x; Greg[4*j4+1] = v.y; Greg[4*j4+2] = v.z; Greg[4*j4+3] = v.w;
        }
    } else {
        // fallback: stage A into At buffer, invert in place, read back
        const float* src = mean0 + r*CC + cb;
        #pragma unroll
        for (int j4 = 0; j4 < 16; ++j4)
            *(float4*)&At[r*LDT + cb + 4*j4] = *(const float4*)&src[4*j4];
        __syncthreads();
        ginv_inplace(sm, t);
        #pragma unroll
        for (int j4 = 0; j4 < 16; ++j4) {
            const float4 v = *(const float4*)&At[r*LDT + cb + 4*j4];
            Greg[4*j4] = v.x; Greg[4*j4+1] = v.y; Greg[4*j4+2] = v.z; Greg[4*j4+3] = v.w;
        }
        __syncthreads();       // done reading Ginv before At is overwritten
    }
    {
        const float* src = mean0 + r*CC + cb;
        #pragma unroll
        for (int j4 = 0; j4 < 16; ++j4) {
            const float4 v = *(const float4*)&src[4*j4];
            Areg[4*j4] = v.x; Areg[4*j4+1] = v.y; Areg[4*j4+2] = v.z; Areg[4*j4+3] = v.w;
        }
    }
    #pragma unroll
    for (int j = 0; j < 64; ++j) Ureg[j] = (cb + j == r) ? pvar : 0.f;
    // At = A^T (consecutive lanes -> consecutive addresses)
    #pragma unroll
    for (int j = 0; j < 64; ++j) At[(cb + j)*LDT + r] = Areg[j];
    if (t < 32)
        *(float4*)&vz[4*t] = *(const float4*)&zin[(size_t)b*CC + 4*t];
    __syncthreads();

    // P0 (prologue): az(0) = A z0
    {
        float s = 0.f;
        #pragma unroll
        for (int j4 = 0; j4 < 16; ++j4) {
            const float4 x = *(const float4*)&vz[cb + 4*j4];
            s += Areg[4*j4]*x.x + Areg[4*j4+1]*x.y + Areg[4*j4+2]*x.z + Areg[4*j4+3]*x.w;
        }
        atomicAdd(&vaz[r], s);
    }
    __syncthreads();

    #pragma unroll 1
    for (int e = 0; e < EE; ++e) {
        const int p  = e & 1;
        const int pp = p ^ 1;
        float* g1p = sm + VEC(5) + (p  << 7);
        float* g1q = sm + VEC(5) + (pp << 7);
        float* g2p = sm + VEC(7) + (p  << 7);
        float* g2q = sm + VEC(7) + (pp << 7);
        float* scp = scal + 8*p;
        float* scq = scal + 8*pp;
        // ---- Pa: Greg -= rank2(prev) ; w = Ginv_new az ; vt2 = z ; zero vuw ----
        {
            const float sigp    = scq[0];
            const float inv_sig = 1.0f / sigp;
            const float d2v     = scq[1];
            const float s_uwg2  = scq[2];
            const float s_vg1   = SIG4 * scq[3];
            const float s_uwg1  = SIG2 * scq[4];
            const float b11  = s_vg1 - d2v;
            const float b12  = 1.0f + s_uwg1*inv_sig;
            const float b22  = s_uwg2*inv_sig*inv_sig;
            const float idet = 1.0f / (b11*b22 - b12*b12);
            const float K11 = b22*idet, K12v = -b12*idet, K22 = b11*idet;
            const float k12s = K12v*inv_sig, k22s = K22*inv_sig*inv_sig;
            const float g1r = SIG2 * g1q[r];
            const float g2r = g2q[r];
            const float ar_ = K11*g1r + k12s*g2r;
            const float br_ = k12s*g1r + k22s*g2r;
            const float ars = ar_ * SIG2;
            float s = 0.f;
            #pragma unroll
            for (int j4 = 0; j4 < 16; ++j4) {
                const float4 q1 = *(const float4*)&g1q[cb + 4*j4];
                const float4 q2 = *(const float4*)&g2q[cb + 4*j4];
                Greg[4*j4]   -= ars*q1.x + br_*q2.x;
                Greg[4*j4+1] -= ars*q1.y + br_*q2.y;
                Greg[4*j4+2] -= ars*q1.z + br_*q2.z;
                Greg[4*j4+3] -= ars*q1.w + br_*q2.w;
                const float4 x = *(const float4*)&vaz[cb + 4*j4];
                s += Greg[4*j4]*x.x + Greg[4*j4+1]*x.y + Greg[4*j4+2]*x.z + Greg[4*j4+3]*x.w;
            }
            atomicAdd(&vw0[r], s);
            if (t < 128) { vt2[t] = vz[t]; vuw[t] = 0.f; }
        }
        __syncthreads();
        // ---- Pb: dl=z-At w ; uw=U w ; g1c=Ginv w ; sig,s_vg1 ; zero prev banks + vaz ; prefetch z ----
        {
            float s1 = 0.f, s2 = 0.f, s3 = 0.f;
            #pragma unroll
            for (int j4 = 0; j4 < 16; ++j4) {
                const float4 a = *(const float4*)&At[r*LDT + cb + 4*j4];
                const float4 x = *(const float4*)&vw0[cb + 4*j4];
                s1 += a.x*x.x + a.y*x.y + a.z*x.z + a.w*x.w;
                s2 += Ureg[4*j4]*x.x + Ureg[4*j4+1]*x.y + Ureg[4*j4+2]*x.z + Ureg[4*j4+3]*x.w;
                s3 += Greg[4*j4]*x.x + Greg[4*j4+1]*x.y + Greg[4*j4+2]*x.z + Greg[4*j4+3]*x.w;
            }
            atomicAdd(&vt2[r], -s1);
            atomicAdd(&vuw[r], s2);
            atomicAdd(&g1p[r], s3);
            const float w_r = vw0[r];
            SC_ADD(scp, 0, s2 * w_r);                  // sig partial (wT U w)
            SC_ADD(scp, 3, s3 * w_r);                  // s_vg1 / SIG4 partial (wT Ginv w)
            if (t < 128) { g1q[t] = 0.f; g2q[t] = 0.f; vaz[t] = 0.f; }
            if (t == 192) { scq[0] = SIG2; scq[1] = 0.f; scq[2] = 0.f; scq[3] = 0.f; scq[4] = 0.f; }
            if (t < 32 && e + 1 < EE)
                *(float4*)&vz[4*t] = *(const float4*)&zin[((size_t)(e+1)*BB + b)*CC + 4*t];
        }
        __syncthreads();
        // ---- Pc: g2=Ginv uw ; s_uwg2,d2,s_uwg1 ; update A,U ; At write ; az_next ; zero vw0 ----
        {
            float s = 0.f;
            #pragma unroll
            for (int j4 = 0; j4 < 16; ++j4) {
                const float4 x = *(const float4*)&vuw[cb + 4*j4];
                s += Greg[4*j4]*x.x + Greg[4*j4+1]*x.y + Greg[4*j4+2]*x.z + Greg[4*j4+3]*x.w;
            }
            atomicAdd(&g2p[r], s);
            SC_ADD(scp, 2, s * vuw[r]);                // s_uwg2 partial (uwT Ginv uw)
            if (t < 128) {
                float d_ = vt2[t]; d_ *= d_;
                d_ += __shfl_xor(d_, 1, 64); d_ += __shfl_xor(d_, 2, 64); d_ += __shfl_xor(d_, 4, 64);
                if ((l & 7) == 0) atomicAdd(&scp[1], d_);        // d2
                float p_ = g1p[t] * vuw[t];
                p_ += __shfl_xor(p_, 1, 64); p_ += __shfl_xor(p_, 2, 64); p_ += __shfl_xor(p_, 4, 64);
                if ((l & 7) == 0) atomicAdd(&scp[4], p_);        // s_uwg1 / SIG2
                vw0[t] = 0.f;
            }
            const float sig = scp[0];                  // accumulated in Pb
            const float inv_sig = 1.0f / sig;
            const float cr = vuw[r] * inv_sig;
            #pragma unroll
            for (int j4 = 0; j4 < 16; ++j4) {
                const float4 dd = *(const float4*)&vt2[cb + 4*j4];
                Areg[4*j4]   += cr*dd.x; Areg[4*j4+1] += cr*dd.y;
                Areg[4*j4+2] += cr*dd.z; Areg[4*j4+3] += cr*dd.w;
                const float4 uu = *(const float4*)&vuw[cb + 4*j4];
                Ureg[4*j4]   -= cr*uu.x; Ureg[4*j4+1] -= cr*uu.y;
                Ureg[4*j4+2] -= cr*uu.z; Ureg[4*j4+3] -= cr*uu.w;
            }
            // write-through A^T
            #pragma unroll
            for (int j = 0; j < 64; ++j) At[(cb + j)*LDT + r] = Areg[j];
            // fused next-step az = A_new z_next (z prefetched in Pb)
            if (e + 1 < EE) {
                float s2 = 0.f;
                #pragma unroll
                for (int j4 = 0; j4 < 16; ++j4) {
                    const float4 x = *(const float4*)&vz[cb + 4*j4];
                    s2 += Areg[4*j4]*x.x + Areg[4*j4+1]*x.y + Areg[4*j4+2]*x.z + Areg[4*j4+3]*x.w;
                }
                atomicAdd(&vaz[r], s2);
            }
        }
        __syncthreads();
    }

    // epilogue: post_mean from Areg
    {
        float* dst = out + (size_t)b*(MM*CC) + r*CC + cb;
        #pragma unroll
        for (int j4 = 0; j4 < 16; ++j4) {
            float4 v; v.x = Areg[4*j4]; v.y = Areg[4*j4+1]; v.z = Areg[4*j4+2]; v.w = Areg[4*j4+3];
            *(float4*)&dst[4*j4] = v;
        }
    }
    // post_cov from Ureg + diag extraction (static indexing)
    float qd = 1.f;
    {
        float* dst = out + (size_t)BB*(MM*CC) + (size_t)b*(MM*MM) + r*MM + cb;
        #pragma unroll
        for (int j4 = 0; j4 < 16; ++j4) {
            float4 v; v.x = Ureg[4*j4]; v.y = Ureg[4*j4+1]; v.z = Ureg[4*j4+2]; v.w = Ureg[4*j4+3];
            *(float4*)&dst[4*j4] = v;
            if (cb + 4*j4     == r) qd = v.x;
            if (cb + 4*j4 + 1 == r) qd = v.y;
            if (cb + 4*j4 + 2 == r) qd = v.z;
            if (cb + 4*j4 + 3 == r) qd = v.w;
        }
    }
    // dkl = mean_b[ C*sum(q/p) + sum((A-A0)^2)/p - C*M + C*sum(log p - log q) ]
    {
        const float inv_p = 1.0f / pvar;
        float acc = 0.f;
        const float* src = mean0 + r*CC + cb;
        #pragma unroll
        for (int j4 = 0; j4 < 16; ++j4) {
            const float4 a0 = *(const float4*)&src[4*j4];
            const float dx = Areg[4*j4]   - a0.x, dy = Areg[4*j4+1] - a0.y;
            const float dz = Areg[4*j4+2] - a0.z, dw = Areg[4*j4+3] - a0.w;
            acc += dx*dx + dy*dy + dz*dz + dw*dw;
        }
        float local = acc * inv_p;
        if (q == (r >> 6))   // owner of diagonal element of row r
            local += (float)CC * (qd*inv_p + logf(pvar) - logf(qd));
        #pragma unroll
        for (int m2 = 1; m2 < 64; m2 <<= 1) local += __shfl_xor(local, m2, 64);
        if (l == 0) scal[16 + w] = local;
        __syncthreads();
        if (t == 0) {
            const float tot = scal[16] + scal[17] + scal[18] + scal[19] - (float)(CC*MM);
            atomicAdd(out + (size_t)2*BB*MM*CC, tot * (1.0f/(float)BB));
        }
    }
}

extern "C" void kernel_launch(void* const* d_in, const int* in_sizes, int n_in,
                              void* d_out, int out_size, void* d_ws, size_t ws_size,
                              hipStream_t stream) {
    (void)in_sizes; (void)n_in; (void)out_size;
    const float* zin   = (const float*)d_in[0];
    const float* mean0 = (const float*)d_in[1];
    const float* lvar  = (const float*)d_in[2];
    float* out = (float*)d_out;
    float* dkl = out + (size_t)2*BB*MM*CC;
    const int use_ws = (d_ws != nullptr && ws_size >= (size_t)MM*MM*4) ? 1 : 0;
    float* ginv0 = (float*)d_ws;

    hipFuncSetAttribute((const void*)gpm_setup, hipFuncAttributeMaxDynamicSharedMemorySize, SMEM_BYTES);
    hipFuncSetAttribute((const void*)gpm_main,  hipFuncAttributeMaxDynamicSharedMemorySize, SMEM_BYTES);

    hipMemsetAsync(dkl, 0, sizeof(float), stream);
    if (use_ws)
        gpm_setup<<<1, 256, SMEM_BYTES, stream>>>(mean0, ginv0);
    gpm_main<<<BB, 256, SMEM_BYTES, stream>>>(zin, mean0, lvar, out, ginv0, use_ws);
}

// Round 14
// 1284.558 us; speedup vs baseline: 1.1110x; 1.1110x over previous
//
#include <hip/hip_runtime.h>
#include <math.h>

// Problem constants (E,B,M,C) = (64, 512, 128, 128), sigma=0.5, eps=1e-6
#define MM   128
#define CC   128
#define EE   64
#define BB   512
#define LDT  132          // padded row stride for At in LDS (measured conflict-free r4-r13)
#define SIG2 0.25f
#define SIG4 0.0625f
#define EPSV 1e-6f

// LDS layout (floats): At[128][132] + 9 vectors of 128 + 32 scalars = 72,320 B
// (At buffer doubles as Gauss-Jordan scratch in the no-workspace fallback.)
#define AT_OFF   0
#define VEC_BASE (128*LDT)
#define VEC(i)   (VEC_BASE + (i)*128)
// vec: 0 vz, 1 vaz, 2 vw0(w), 3 vt2(z->dl), 4 vuw, 5 g1-bank0, 6 g1-bank1, 7 g2-bank0, 8 g2-bank1
#define SC_OFF   (VEC_BASE + 9*128)
// scal: [0..7]=bank0, [8..15]=bank1 ([+0]=sig [+1]=d2 [+2]=s_uwg2 [+3]=s_vg1/SIG4 [+4]=s_uwg1/SIG2)
//       [16..23]=epilogue wave sums, [30]=GJ pivot
#define SMEM_FLOATS (SC_OFF + 32)
#define SMEM_BYTES  (SMEM_FLOATS * 4)    // 72,320 B

// ---------------------------------------------------------------------------
// 512 threads = 8 waves: w = t>>6, l = t&63
//   r = 64*(w&1)+l (row owned), q = w>>1 (0..3), cb = 32*q (column chunk)
// REGISTERS: Areg[32] + Ureg[32] + Greg[32] = 96 state. LDS: At + vectors.
// DS-PIPE MODEL (r12 counters + m134 cycle constants): phases are LDS-
// throughput bound; U's LDS residency cost 24 b128/thread/step (Pb read +
// Pc rmw). U in regs adds ZERO new loads: Pb's U-matvec shares x=w with the
// At/Ginv matvecs; Pc's U-update shares x=vuw with the g2 matvec.
// PRESSURE CONTROL (r5 spilled this state config with fused loops):
// Pc split into two passes (g2+U-update | A-update+az) so <=2 float4 temps
// live; budget 128 via waves_per_eu(1,2) (law: budget = 256/max).
// TRIPWIRE: hbm_bytes >= 5e8 => spilled => revert to r12.
// 3-phase deferred-Ginv schedule + v = SIG2*w identity carried from r12.
// Occupancy pins at 1 block/CU in every measured config (r1-r13) — design
// accepts it; the lever is DS-pipe work per phase.
// ---------------------------------------------------------------------------
#define KATTR __attribute__((amdgpu_flat_work_group_size(512, 512), amdgpu_waves_per_eu(1, 2)))

// In-place Gauss-Jordan inverse of (A A^T + SIG2*I), 512 threads.
// A staged row-major in T=[128][LDT]; destroys T; leaves Ginv in T.
// Map: rg = t>>2, cq = t&3, ccb = 32*cq.   (verbatim from passing r5-r12)
__device__ __forceinline__ void ginv_inplace(float* sm, const int t) {
    float* T   = sm + AT_OFF;
    float* piv = sm + SC_OFF + 30;
    const int rg = t >> 2, cq = t & 3, ccb = cq << 5;
    float Gacc[32];
    #pragma unroll
    for (int j = 0; j < 32; ++j) Gacc[j] = 0.f;
    #pragma unroll 1
    for (int cc = 0; cc < 32; ++cc) {
        const float4 ar = *(const float4*)&T[rg*LDT + 4*cc];
        #pragma unroll
        for (int j = 0; j < 32; ++j) {
            const float4 br = *(const float4*)&T[(ccb + j)*LDT + 4*cc];
            Gacc[j] += ar.x*br.x + ar.y*br.y + ar.z*br.z + ar.w*br.w;
        }
    }
    #pragma unroll
    for (int j = 0; j < 32; ++j)
        if (ccb + j == rg) Gacc[j] += SIG2;
    __syncthreads();
    #pragma unroll
    for (int j4 = 0; j4 < 8; ++j4) {
        float4 v; v.x = Gacc[4*j4]; v.y = Gacc[4*j4+1]; v.z = Gacc[4*j4+2]; v.w = Gacc[4*j4+3];
        *(float4*)&T[rg*LDT + ccb + 4*j4] = v;
    }
    #pragma unroll 1
    for (int k = 0; k < 128; ++k) {
        const int kq = k >> 5;
        __syncthreads();
        if (rg == k && cq == kq) piv[0] = 1.0f / T[k*LDT + k];
        __syncthreads();
        if (rg == k) {
            const float pinv = piv[0];
            #pragma unroll
            for (int j4 = 0; j4 < 8; ++j4) {
                float4 g = *(float4*)&T[k*LDT + ccb + 4*j4];
                g.x *= pinv; g.y *= pinv; g.z *= pinv; g.w *= pinv;
                *(float4*)&T[k*LDT + ccb + 4*j4] = g;
            }
            if (cq == kq) T[k*LDT + k] = pinv;   // identity-column trick
        }
        __syncthreads();
        const float f = (rg == k) ? 0.f : T[rg*LDT + k];
        __syncthreads();
        if (rg != k) {
            #pragma unroll
            for (int j4 = 0; j4 < 8; ++j4) {
                float4 own = *(float4*)&T[rg*LDT + ccb + 4*j4];
                const float4 pv = *(const float4*)&T[k*LDT + ccb + 4*j4];
                own.x -= f*pv.x; own.y -= f*pv.y; own.z -= f*pv.z; own.w -= f*pv.w;
                *(float4*)&T[rg*LDT + ccb + 4*j4] = own;
            }
            if (cq == kq) T[rg*LDT + k] -= f;    // blind gave f - f*pinv; want -f*pinv
        }
    }
    __syncthreads();
}

__global__ KATTR void gpm_setup(const float* __restrict__ mean0,
                                float* __restrict__ ginv0) {
    extern __shared__ float sm[];
    float* T = sm + AT_OFF;
    const int t = threadIdx.x;
    const int rg = t >> 2, cq = t & 3, ccb = cq << 5;
    const float* src = mean0 + rg*CC + ccb;
    #pragma unroll
    for (int j4 = 0; j4 < 8; ++j4)
        *(float4*)&T[rg*LDT + ccb + 4*j4] = *(const float4*)&src[4*j4];
    __syncthreads();
    ginv_inplace(sm, t);
    #pragma unroll
    for (int j4 = 0; j4 < 8; ++j4)
        *(float4*)&ginv0[rg*CC + ccb + 4*j4] = *(const float4*)&T[rg*LDT + ccb + 4*j4];
}

// 3-level shuffle (8-lane groups) then 1-in-8 lanes atomic into a scalar slot
#define SC_ADD(base, slot, val) { float v_ = (val);                           \
    v_ += __shfl_xor(v_, 1, 64); v_ += __shfl_xor(v_, 2, 64);                 \
    v_ += __shfl_xor(v_, 4, 64);                                              \
    if ((l & 7) == 0) atomicAdd(&(base)[slot], v_); }

__global__ KATTR void gpm_main(
        const float* __restrict__ zin, const float* __restrict__ mean0,
        const float* __restrict__ lvar, float* __restrict__ out,
        const float* __restrict__ ginv0, const int use_ws) {
    extern __shared__ float sm[];
    float* At  = sm + AT_OFF;
    float* vz  = sm + VEC(0);
    float* vaz = sm + VEC(1);
    float* vw0 = sm + VEC(2);
    float* vt2 = sm + VEC(3);   // z copy in Pa; dl after Pb
    float* vuw = sm + VEC(4);
    float* scal = sm + SC_OFF;

    const int t = threadIdx.x, b = blockIdx.x;
    const int w = t >> 6, l = t & 63;
    const int r  = ((w & 1) << 6) | l;
    const int q  = w >> 1;
    const int cb = q << 5;

    const float pvar = expf(lvar[0]) + EPSV;

    float Areg[32], Ureg[32], Greg[32];

    if (use_ws) {
        const float* src = ginv0 + r*CC + cb;
        #pragma unroll
        for (int j4 = 0; j4 < 8; ++j4) {
            const float4 v = *(const float4*)&src[4*j4];
            Greg[4*j4] = v.x; Greg[4*j4+1] = v.y; Greg[4*j4+2] = v.z; Greg[4*j4+3] = v.w;
        }
    } else {
        // fallback: stage A into At buffer (scratch), invert in place, read back
        const float* src = mean0 + r*CC + cb;
        #pragma unroll
        for (int j4 = 0; j4 < 8; ++j4)
            *(float4*)&At[r*LDT + cb + 4*j4] = *(const float4*)&src[4*j4];
        __syncthreads();
        ginv_inplace(sm, t);
        #pragma unroll
        for (int j4 = 0; j4 < 8; ++j4) {
            const float4 v = *(const float4*)&At[r*LDT + cb + 4*j4];
            Greg[4*j4] = v.x; Greg[4*j4+1] = v.y; Greg[4*j4+2] = v.z; Greg[4*j4+3] = v.w;
        }
        __syncthreads();       // done reading Ginv before At is overwritten
    }
    // zero accumulator vectors VEC(1)..VEC(8) (1024 floats) + scalar slots
    sm[VEC(1) + t] = 0.f;
    sm[VEC(1) + 512 + t] = 0.f;
    if (t < 32) scal[t] = 0.f;
    {
        const float* src = mean0 + r*CC + cb;
        #pragma unroll
        for (int j4 = 0; j4 < 8; ++j4) {
            const float4 v = *(const float4*)&src[4*j4];
            Areg[4*j4] = v.x; Areg[4*j4+1] = v.y; Areg[4*j4+2] = v.z; Areg[4*j4+3] = v.w;
        }
    }
    #pragma unroll
    for (int j = 0; j < 32; ++j) Ureg[j] = (cb + j == r) ? pvar : 0.f;
    // At = A^T (consecutive lanes -> consecutive addresses)
    #pragma unroll
    for (int j = 0; j < 32; ++j) At[(cb + j)*LDT + r] = Areg[j];
    if (t < 32)
        *(float4*)&vz[4*t] = *(const float4*)&zin[(size_t)b*CC + 4*t];
    __syncthreads();
    if (t == 0) { scal[0] = SIG2; scal[8] = SIG2; }   // sig slots of both banks

    // P0 (prologue): az(0) = A z0
    {
        float s = 0.f;
        #pragma unroll
        for (int j4 = 0; j4 < 8; ++j4) {
            const float4 x = *(const float4*)&vz[cb + 4*j4];
            s += Areg[4*j4]*x.x + Areg[4*j4+1]*x.y + Areg[4*j4+2]*x.z + Areg[4*j4+3]*x.w;
        }
        atomicAdd(&vaz[r], s);
    }
    __syncthreads();

    #pragma unroll 1
    for (int e = 0; e < EE; ++e) {
        const int p  = e & 1;
        const int pp = p ^ 1;
        float* g1p = sm + VEC(5) + (p  << 7);
        float* g1q = sm + VEC(5) + (pp << 7);
        float* g2p = sm + VEC(7) + (p  << 7);
        float* g2q = sm + VEC(7) + (pp << 7);
        float* scp = scal + 8*p;
        float* scq = scal + 8*pp;
        // ---- Pa: Greg -= rank2(prev) ; w = Ginv_new az ; vt2 = z ; zero vuw ----
        {
            const float sigp    = scq[0];
            const float inv_sig = 1.0f / sigp;
            const float d2v     = scq[1];
            const float s_uwg2  = scq[2];
            const float s_vg1   = SIG4 * scq[3];
            const float s_uwg1  = SIG2 * scq[4];
            const float b11  = s_vg1 - d2v;
            const float b12  = 1.0f + s_uwg1*inv_sig;
            const float b22  = s_uwg2*inv_sig*inv_sig;
            const float idet = 1.0f / (b11*b22 - b12*b12);
            const float K11 = b22*idet, K12v = -b12*idet, K22 = b11*idet;
            const float k12s = K12v*inv_sig, k22s = K22*inv_sig*inv_sig;
            const float g1r = SIG2 * g1q[r];
            const float g2r = g2q[r];
            const float ar_ = K11*g1r + k12s*g2r;
            const float br_ = k12s*g1r + k22s*g2r;
            const float ars = ar_ * SIG2;
            float s = 0.f;
            #pragma unroll
            for (int j4 = 0; j4 < 8; ++j4) {
                const float4 q1 = *(const float4*)&g1q[cb + 4*j4];
                const float4 q2 = *(const float4*)&g2q[cb + 4*j4];
                Greg[4*j4]   -= ars*q1.x + br_*q2.x;
                Greg[4*j4+1] -= ars*q1.y + br_*q2.y;
                Greg[4*j4+2] -= ars*q1.z + br_*q2.z;
                Greg[4*j4+3] -= ars*q1.w + br_*q2.w;
                const float4 x = *(const float4*)&vaz[cb + 4*j4];
                s += Greg[4*j4]*x.x + Greg[4*j4+1]*x.y + Greg[4*j4+2]*x.z + Greg[4*j4+3]*x.w;
            }
            atomicAdd(&vw0[r], s);
            if (t < 128) { vt2[t] = vz[t]; vuw[t] = 0.f; }
        }
        __syncthreads();
        // ---- Pb: dl=z-At w ; uw=U w (regs) ; g1c=Ginv w ; sig,s_vg1 ; zero prev banks + vaz ; prefetch z ----
        {
            float s1 = 0.f, s2 = 0.f, s3 = 0.f;
            #pragma unroll
            for (int j4 = 0; j4 < 8; ++j4) {
                const float4 a = *(const float4*)&At[r*LDT + cb + 4*j4];
                const float4 x = *(const float4*)&vw0[cb + 4*j4];
                s1 += a.x*x.x + a.y*x.y + a.z*x.z + a.w*x.w;
                s2 += Ureg[4*j4]*x.x + Ureg[4*j4+1]*x.y + Ureg[4*j4+2]*x.z + Ureg[4*j4+3]*x.w;
                s3 += Greg[4*j4]*x.x + Greg[4*j4+1]*x.y + Greg[4*j4+2]*x.z + Greg[4*j4+3]*x.w;
            }
            atomicAdd(&vt2[r], -s1);
            atomicAdd(&vuw[r], s2);
            atomicAdd(&g1p[r], s3);
            const float w_r = vw0[r];
            SC_ADD(scp, 0, s2 * w_r);                  // sig partial (wT U w)
            SC_ADD(scp, 3, s3 * w_r);                  // s_vg1 / SIG4 partial (wT Ginv w)
            if (t < 128) { g1q[t] = 0.f; g2q[t] = 0.f; vaz[t] = 0.f; }
            if (t == 448) { scq[0] = SIG2; scq[1] = 0.f; scq[2] = 0.f; scq[3] = 0.f; scq[4] = 0.f; }
            if (t < 32 && e + 1 < EE)
                *(float4*)&vz[4*t] = *(const float4*)&zin[((size_t)(e+1)*BB + b)*CC + 4*t];
        }
        __syncthreads();
        // ---- Pc: pass1 {g2 = Ginv uw ; U -= c uw^T} sharing x=vuw ;
        //          scalars (s_uwg2, d2, s_uwg1) ;
        //          pass2 {A += c dl^T ; At write ; az_next} ; zero vw0 ----
        {
            const float sig = scp[0];                  // accumulated in Pb
            const float inv_sig = 1.0f / sig;
            const float cr = vuw[r] * inv_sig;
            float s = 0.f;
            #pragma unroll
            for (int j4 = 0; j4 < 8; ++j4) {
                const float4 x = *(const float4*)&vuw[cb + 4*j4];
                s += Greg[4*j4]*x.x + Greg[4*j4+1]*x.y + Greg[4*j4+2]*x.z + Greg[4*j4+3]*x.w;
                Ureg[4*j4]   -= cr*x.x; Ureg[4*j4+1] -= cr*x.y;
                Ureg[4*j4+2] -= cr*x.z; Ureg[4*j4+3] -= cr*x.w;
            }
            atomicAdd(&g2p[r], s);
            SC_ADD(scp, 2, s * vuw[r]);                // s_uwg2 partial (uwT Ginv uw)
            if (t < 128) {
                float d_ = vt2[t]; d_ *= d_;
                d_ += __shfl_xor(d_, 1, 64); d_ += __shfl_xor(d_, 2, 64); d_ += __shfl_xor(d_, 4, 64);
                if ((l & 7) == 0) atomicAdd(&scp[1], d_);        // d2
                float p_ = g1p[t] * vuw[t];
                p_ += __shfl_xor(p_, 1, 64); p_ += __shfl_xor(p_, 2, 64); p_ += __shfl_xor(p_, 4, 64);
                if ((l & 7) == 0) atomicAdd(&scp[4], p_);        // s_uwg1 / SIG2
                vw0[t] = 0.f;
            }
            #pragma unroll
            for (int j4 = 0; j4 < 8; ++j4) {
                const float4 dd = *(const float4*)&vt2[cb + 4*j4];
                Areg[4*j4]   += cr*dd.x; Areg[4*j4+1] += cr*dd.y;
                Areg[4*j4+2] += cr*dd.z; Areg[4*j4+3] += cr*dd.w;
            }
            // write-through A^T
            #pragma unroll
            for (int j = 0; j < 32; ++j) At[(cb + j)*LDT + r] = Areg[j];
            // fused next-step az = A_new z_next (z prefetched in Pb)
            if (e + 1 < EE) {
                float s2 = 0.f;
                #pragma unroll
                for (int j4 = 0; j4 < 8; ++j4) {
                    const float4 x = *(const float4*)&vz[cb + 4*j4];
                    s2 += Areg[4*j4]*x.x + Areg[4*j4+1]*x.y + Areg[4*j4+2]*x.z + Areg[4*j4+3]*x.w;
                }
                atomicAdd(&vaz[r], s2);
            }
        }
        __syncthreads();
    }

    // epilogue: post_mean from Areg
    {
        float* dst = out + (size_t)b*(MM*CC) + r*CC + cb;
        #pragma unroll
        for (int j4 = 0; j4 < 8; ++j4) {
            float4 v; v.x = Areg[4*j4]; v.y = Areg[4*j4+1]; v.z = Areg[4*j4+2]; v.w = Areg[4*j4+3];
            *(float4*)&dst[4*j4] = v;
        }
    }
    // post_cov from Ureg + diag extraction (static indexing)
    float qd = 1.f;
    {
        float* dst = out + (size_t)BB*(MM*CC) + (size_t)b*(MM*MM) + r*MM + cb;
        #pragma unroll
        for (int j4 = 0; j4 < 8; ++j4) {
            float4 v; v.x = Ureg[4*j4]; v.y = Ureg[4*j4+1]; v.z = Ureg[4*j4+2]; v.w = Ureg[4*j4+3];
            *(float4*)&dst[4*j4] = v;
            if (cb + 4*j4     == r) qd = v.x;
            if (cb + 4*j4 + 1 == r) qd = v.y;
            if (cb + 4*j4 + 2 == r) qd = v.z;
            if (cb + 4*j4 + 3 == r) qd = v.w;
        }
    }
    // dkl = mean_b[ C*sum(q/p) + sum((A-A0)^2)/p - C*M + C*sum(log p - log q) ]
    {
        const float inv_p = 1.0f / pvar;
        float acc = 0.f;
        const float* src = mean0 + r*CC + cb;
        #pragma unroll
        for (int j4 = 0; j4 < 8; ++j4) {
            const float4 a0 = *(const float4*)&src[4*j4];
            const float dx = Areg[4*j4]   - a0.x, dy = Areg[4*j4+1] - a0.y;
            const float dz = Areg[4*j4+2] - a0.z, dw = Areg[4*j4+3] - a0.w;
            acc += dx*dx + dy*dy + dz*dz + dw*dw;
        }
        float local = acc * inv_p;
        if (q == (r >> 5))   // owner of diagonal element of row r
            local += (float)CC * (qd*inv_p + logf(pvar) - logf(qd));
        #pragma unroll
        for (int m2 = 1; m2 < 64; m2 <<= 1) local += __shfl_xor(local, m2, 64);
        if (l == 0) scal[16 + w] = local;
        __syncthreads();
        if (t == 0) {
            float tot = 0.f;
            #pragma unroll
            for (int i = 0; i < 8; ++i) tot += scal[16 + i];
            tot -= (float)(CC*MM);
            atomicAdd(out + (size_t)2*BB*MM*CC, tot * (1.0f/(float)BB));
        }
    }
}

extern "C" void kernel_launch(void* const* d_in, const int* in_sizes, int n_in,
                              void* d_out, int out_size, void* d_ws, size_t ws_size,
                              hipStream_t stream) {
    (void)in_sizes; (void)n_in; (void)out_size;
    const float* zin   = (const float*)d_in[0];
    const float* mean0 = (const float*)d_in[1];
    const float* lvar  = (const float*)d_in[2];
    float* out = (float*)d_out;
    float* dkl = out + (size_t)2*BB*MM*CC;
    const int use_ws = (d_ws != nullptr && ws_size >= (size_t)MM*MM*4) ? 1 : 0;
    float* ginv0 = (float*)d_ws;

    hipFuncSetAttribute((const void*)gpm_setup, hipFuncAttributeMaxDynamicSharedMemorySize, SMEM_BYTES);
    hipFuncSetAttribute((const void*)gpm_main,  hipFuncAttributeMaxDynamicSharedMemorySize, SMEM_BYTES);

    hipMemsetAsync(dkl, 0, sizeof(float), stream);
    if (use_ws)
        gpm_setup<<<1, 512, SMEM_BYTES, stream>>>(mean0, ginv0);
    gpm_main<<<BB, 512, SMEM_BYTES, stream>>>(zin, mean0, lvar, out, ginv0, use_ws);
}

// Round 15
// 1282.564 us; speedup vs baseline: 1.1127x; 1.0016x over previous
//
#include <hip/hip_runtime.h>
#include <math.h>

// Problem constants (E,B,M,C) = (64, 512, 128, 128), sigma=0.5, eps=1e-6
#define MM   128
#define CC   128
#define EE   64
#define BB   512
#define LDT  132          // padded row stride for At in LDS (measured conflict-free r4-r14)
#define SIG2 0.25f
#define SIG4 0.0625f
#define EPSV 1e-6f

// LDS layout (floats): At[128][132] + 9 vectors of 128 + 32 scalars = 72,320 B
// -> 2 blocks/CU co-resident (2 x 72.3 KB = 144.6 <= 160 KB).
#define AT_OFF   0
#define VEC_BASE (128*LDT)
#define VEC(i)   (VEC_BASE + (i)*128)
// vec: 0 vz, 1 vaz, 2 vw0(w), 3 vt2(z->dl), 4 vuw, 5 g1-bank0, 6 g1-bank1, 7 g2-bank0, 8 g2-bank1
#define SC_OFF   (VEC_BASE + 9*128)
// scal: [0..7]=bank0, [8..15]=bank1 ([+0]=sig [+1]=d2 [+2]=s_uwg2 [+3]=s_vg1/SIG4 [+4]=s_uwg1/SIG2)
//       [16..23]=epilogue wave sums, [30]=GJ pivot
#define SMEM_FLOATS (SC_OFF + 32)
#define SMEM_BYTES  (SMEM_FLOATS * 4)    // 72,320 B

// ---------------------------------------------------------------------------
// 512 threads = 8 waves: w = t>>6, l = t&63
//   r = 64*(w&1)+l (row owned), q = w>>1 (0..3), cb = 32*q (column chunk)
// REGISTERS: Areg[32] + Ureg[32] + Greg[32] = 96 state (112 VGPR measured r14).
// CO-RESIDENCY (the r15 change): NO waves_per_eu attribute. r13 showed its
// max is a RUNTIME occupancy cap (r14's (1,2) pinned 8 waves/CU = 1 block);
// r3 showed the default heuristic gives 512-thr kernels a 128-VGPR budget.
// Footprint now fits two blocks/CU (LDS 2x72.3<=160 KB, VGPR 16x112<=2048),
// so dropping the attr lets block B's matvecs fill block A's barrier-drain
// bubbles (r14: DS pipe only ~49% busy) and the 512-block grid runs in ONE
// generation. TRIPWIRES: VGPR=64 => heuristic spilled => revert to r14 attr;
// Occupancy stays 24% => no co-residency => perf unchanged (downside-free).
// 3-phase deferred-Ginv schedule + v = SIG2*w identity carried from r12-r14.
// ---------------------------------------------------------------------------
#define KATTR __attribute__((amdgpu_flat_work_group_size(512, 512)))

// In-place Gauss-Jordan inverse of (A A^T + SIG2*I), 512 threads.
// A staged row-major in T=[128][LDT]; destroys T; leaves Ginv in T.
// Map: rg = t>>2, cq = t&3, ccb = 32*cq.   (verbatim from passing r5-r14)
__device__ __forceinline__ void ginv_inplace(float* sm, const int t) {
    float* T   = sm + AT_OFF;
    float* piv = sm + SC_OFF + 30;
    const int rg = t >> 2, cq = t & 3, ccb = cq << 5;
    float Gacc[32];
    #pragma unroll
    for (int j = 0; j < 32; ++j) Gacc[j] = 0.f;
    #pragma unroll 1
    for (int cc = 0; cc < 32; ++cc) {
        const float4 ar = *(const float4*)&T[rg*LDT + 4*cc];
        #pragma unroll
        for (int j = 0; j < 32; ++j) {
            const float4 br = *(const float4*)&T[(ccb + j)*LDT + 4*cc];
            Gacc[j] += ar.x*br.x + ar.y*br.y + ar.z*br.z + ar.w*br.w;
        }
    }
    #pragma unroll
    for (int j = 0; j < 32; ++j)
        if (ccb + j == rg) Gacc[j] += SIG2;
    __syncthreads();
    #pragma unroll
    for (int j4 = 0; j4 < 8; ++j4) {
        float4 v; v.x = Gacc[4*j4]; v.y = Gacc[4*j4+1]; v.z = Gacc[4*j4+2]; v.w = Gacc[4*j4+3];
        *(float4*)&T[rg*LDT + ccb + 4*j4] = v;
    }
    #pragma unroll 1
    for (int k = 0; k < 128; ++k) {
        const int kq = k >> 5;
        __syncthreads();
        if (rg == k && cq == kq) piv[0] = 1.0f / T[k*LDT + k];
        __syncthreads();
        if (rg == k) {
            const float pinv = piv[0];
            #pragma unroll
            for (int j4 = 0; j4 < 8; ++j4) {
                float4 g = *(float4*)&T[k*LDT + ccb + 4*j4];
                g.x *= pinv; g.y *= pinv; g.z *= pinv; g.w *= pinv;
                *(float4*)&T[k*LDT + ccb + 4*j4] = g;
            }
            if (cq == kq) T[k*LDT + k] = pinv;   // identity-column trick
        }
        __syncthreads();
        const float f = (rg == k) ? 0.f : T[rg*LDT + k];
        __syncthreads();
        if (rg != k) {
            #pragma unroll
            for (int j4 = 0; j4 < 8; ++j4) {
                float4 own = *(float4*)&T[rg*LDT + ccb + 4*j4];
                const float4 pv = *(const float4*)&T[k*LDT + ccb + 4*j4];
                own.x -= f*pv.x; own.y -= f*pv.y; own.z -= f*pv.z; own.w -= f*pv.w;
                *(float4*)&T[rg*LDT + ccb + 4*j4] = own;
            }
            if (cq == kq) T[rg*LDT + k] -= f;    // blind gave f - f*pinv; want -f*pinv
        }
    }
    __syncthreads();
}

__global__ KATTR void gpm_setup(const float* __restrict__ mean0,
                                float* __restrict__ ginv0) {
    extern __shared__ float sm[];
    float* T = sm + AT_OFF;
    const int t = threadIdx.x;
    const int rg = t >> 2, cq = t & 3, ccb = cq << 5;
    const float* src = mean0 + rg*CC + ccb;
    #pragma unroll
    for (int j4 = 0; j4 < 8; ++j4)
        *(float4*)&T[rg*LDT + ccb + 4*j4] = *(const float4*)&src[4*j4];
    __syncthreads();
    ginv_inplace(sm, t);
    #pragma unroll
    for (int j4 = 0; j4 < 8; ++j4)
        *(float4*)&ginv0[rg*CC + ccb + 4*j4] = *(const float4*)&T[rg*LDT + ccb + 4*j4];
}

// 3-level shuffle (8-lane groups) then 1-in-8 lanes atomic into a scalar slot
#define SC_ADD(base, slot, val) { float v_ = (val);                           \
    v_ += __shfl_xor(v_, 1, 64); v_ += __shfl_xor(v_, 2, 64);                 \
    v_ += __shfl_xor(v_, 4, 64);                                              \
    if ((l & 7) == 0) atomicAdd(&(base)[slot], v_); }

__global__ KATTR void gpm_main(
        const float* __restrict__ zin, const float* __restrict__ mean0,
        const float* __restrict__ lvar, float* __restrict__ out,
        const float* __restrict__ ginv0, const int use_ws) {
    extern __shared__ float sm[];
    float* At  = sm + AT_OFF;
    float* vz  = sm + VEC(0);
    float* vaz = sm + VEC(1);
    float* vw0 = sm + VEC(2);
    float* vt2 = sm + VEC(3);   // z copy in Pa; dl after Pb
    float* vuw = sm + VEC(4);
    float* scal = sm + SC_OFF;

    const int t = threadIdx.x, b = blockIdx.x;
    const int w = t >> 6, l = t & 63;
    const int r  = ((w & 1) << 6) | l;
    const int q  = w >> 1;
    const int cb = q << 5;

    const float pvar = expf(lvar[0]) + EPSV;

    float Areg[32], Ureg[32], Greg[32];

    if (use_ws) {
        const float* src = ginv0 + r*CC + cb;
        #pragma unroll
        for (int j4 = 0; j4 < 8; ++j4) {
            const float4 v = *(const float4*)&src[4*j4];
            Greg[4*j4] = v.x; Greg[4*j4+1] = v.y; Greg[4*j4+2] = v.z; Greg[4*j4+3] = v.w;
        }
    } else {
        // fallback: stage A into At buffer (scratch), invert in place, read back
        const float* src = mean0 + r*CC + cb;
        #pragma unroll
        for (int j4 = 0; j4 < 8; ++j4)
            *(float4*)&At[r*LDT + cb + 4*j4] = *(const float4*)&src[4*j4];
        __syncthreads();
        ginv_inplace(sm, t);
        #pragma unroll
        for (int j4 = 0; j4 < 8; ++j4) {
            const float4 v = *(const float4*)&At[r*LDT + cb + 4*j4];
            Greg[4*j4] = v.x; Greg[4*j4+1] = v.y; Greg[4*j4+2] = v.z; Greg[4*j4+3] = v.w;
        }
        __syncthreads();       // done reading Ginv before At is overwritten
    }
    // zero accumulator vectors VEC(1)..VEC(8) (1024 floats) + scalar slots
    sm[VEC(1) + t] = 0.f;
    sm[VEC(1) + 512 + t] = 0.f;
    if (t < 32) scal[t] = 0.f;
    {
        const float* src = mean0 + r*CC + cb;
        #pragma unroll
        for (int j4 = 0; j4 < 8; ++j4) {
            const float4 v = *(const float4*)&src[4*j4];
            Areg[4*j4] = v.x; Areg[4*j4+1] = v.y; Areg[4*j4+2] = v.z; Areg[4*j4+3] = v.w;
        }
    }
    #pragma unroll
    for (int j = 0; j < 32; ++j) Ureg[j] = (cb + j == r) ? pvar : 0.f;
    // At = A^T (consecutive lanes -> consecutive addresses)
    #pragma unroll
    for (int j = 0; j < 32; ++j) At[(cb + j)*LDT + r] = Areg[j];
    if (t < 32)
        *(float4*)&vz[4*t] = *(const float4*)&zin[(size_t)b*CC + 4*t];
    __syncthreads();
    if (t == 0) { scal[0] = SIG2; scal[8] = SIG2; }   // sig slots of both banks

    // P0 (prologue): az(0) = A z0
    {
        float s = 0.f;
        #pragma unroll
        for (int j4 = 0; j4 < 8; ++j4) {
            const float4 x = *(const float4*)&vz[cb + 4*j4];
            s += Areg[4*j4]*x.x + Areg[4*j4+1]*x.y + Areg[4*j4+2]*x.z + Areg[4*j4+3]*x.w;
        }
        atomicAdd(&vaz[r], s);
    }
    __syncthreads();

    #pragma unroll 1
    for (int e = 0; e < EE; ++e) {
        const int p  = e & 1;
        const int pp = p ^ 1;
        float* g1p = sm + VEC(5) + (p  << 7);
        float* g1q = sm + VEC(5) + (pp << 7);
        float* g2p = sm + VEC(7) + (p  << 7);
        float* g2q = sm + VEC(7) + (pp << 7);
        float* scp = scal + 8*p;
        float* scq = scal + 8*pp;
        // ---- Pa: Greg -= rank2(prev) ; w = Ginv_new az ; vt2 = z ; zero vuw ----
        {
            const float sigp    = scq[0];
            const float inv_sig = 1.0f / sigp;
            const float d2v     = scq[1];
            const float s_uwg2  = scq[2];
            const float s_vg1   = SIG4 * scq[3];
            const float s_uwg1  = SIG2 * scq[4];
            const float b11  = s_vg1 - d2v;
            const float b12  = 1.0f + s_uwg1*inv_sig;
            const float b22  = s_uwg2*inv_sig*inv_sig;
            const float idet = 1.0f / (b11*b22 - b12*b12);
            const float K11 = b22*idet, K12v = -b12*idet, K22 = b11*idet;
            const float k12s = K12v*inv_sig, k22s = K22*inv_sig*inv_sig;
            const float g1r = SIG2 * g1q[r];
            const float g2r = g2q[r];
            const float ar_ = K11*g1r + k12s*g2r;
            const float br_ = k12s*g1r + k22s*g2r;
            const float ars = ar_ * SIG2;
            float s = 0.f;
            #pragma unroll
            for (int j4 = 0; j4 < 8; ++j4) {
                const float4 q1 = *(const float4*)&g1q[cb + 4*j4];
                const float4 q2 = *(const float4*)&g2q[cb + 4*j4];
                Greg[4*j4]   -= ars*q1.x + br_*q2.x;
                Greg[4*j4+1] -= ars*q1.y + br_*q2.y;
                Greg[4*j4+2] -= ars*q1.z + br_*q2.z;
                Greg[4*j4+3] -= ars*q1.w + br_*q2.w;
                const float4 x = *(const float4*)&vaz[cb + 4*j4];
                s += Greg[4*j4]*x.x + Greg[4*j4+1]*x.y + Greg[4*j4+2]*x.z + Greg[4*j4+3]*x.w;
            }
            atomicAdd(&vw0[r], s);
            if (t < 128) { vt2[t] = vz[t]; vuw[t] = 0.f; }
        }
        __syncthreads();
        // ---- Pb: dl=z-At w ; uw=U w (regs) ; g1c=Ginv w ; sig,s_vg1 ; zero prev banks + vaz ; prefetch z ----
        {
            float s1 = 0.f, s2 = 0.f, s3 = 0.f;
            #pragma unroll
            for (int j4 = 0; j4 < 8; ++j4) {
                const float4 a = *(const float4*)&At[r*LDT + cb + 4*j4];
                const float4 x = *(const float4*)&vw0[cb + 4*j4];
                s1 += a.x*x.x + a.y*x.y + a.z*x.z + a.w*x.w;
                s2 += Ureg[4*j4]*x.x + Ureg[4*j4+1]*x.y + Ureg[4*j4+2]*x.z + Ureg[4*j4+3]*x.w;
                s3 += Greg[4*j4]*x.x + Greg[4*j4+1]*x.y + Greg[4*j4+2]*x.z + Greg[4*j4+3]*x.w;
            }
            atomicAdd(&vt2[r], -s1);
            atomicAdd(&vuw[r], s2);
            atomicAdd(&g1p[r], s3);
            const float w_r = vw0[r];
            SC_ADD(scp, 0, s2 * w_r);                  // sig partial (wT U w)
            SC_ADD(scp, 3, s3 * w_r);                  // s_vg1 / SIG4 partial (wT Ginv w)
            if (t < 128) { g1q[t] = 0.f; g2q[t] = 0.f; vaz[t] = 0.f; }
            if (t == 448) { scq[0] = SIG2; scq[1] = 0.f; scq[2] = 0.f; scq[3] = 0.f; scq[4] = 0.f; }
            if (t < 32 && e + 1 < EE)
                *(float4*)&vz[4*t] = *(const float4*)&zin[((size_t)(e+1)*BB + b)*CC + 4*t];
        }
        __syncthreads();
        // ---- Pc: pass1 {g2 = Ginv uw ; U -= c uw^T} sharing x=vuw ;
        //          scalars (s_uwg2, d2, s_uwg1) ;
        //          pass2 {A += c dl^T ; At write ; az_next} ; zero vw0 ----
        {
            const float sig = scp[0];                  // accumulated in Pb
            const float inv_sig = 1.0f / sig;
            const float cr = vuw[r] * inv_sig;
            float s = 0.f;
            #pragma unroll
            for (int j4 = 0; j4 < 8; ++j4) {
                const float4 x = *(const float4*)&vuw[cb + 4*j4];
                s += Greg[4*j4]*x.x + Greg[4*j4+1]*x.y + Greg[4*j4+2]*x.z + Greg[4*j4+3]*x.w;
                Ureg[4*j4]   -= cr*x.x; Ureg[4*j4+1] -= cr*x.y;
                Ureg[4*j4+2] -= cr*x.z; Ureg[4*j4+3] -= cr*x.w;
            }
            atomicAdd(&g2p[r], s);
            SC_ADD(scp, 2, s * vuw[r]);                // s_uwg2 partial (uwT Ginv uw)
            if (t < 128) {
                float d_ = vt2[t]; d_ *= d_;
                d_ += __shfl_xor(d_, 1, 64); d_ += __shfl_xor(d_, 2, 64); d_ += __shfl_xor(d_, 4, 64);
                if ((l & 7) == 0) atomicAdd(&scp[1], d_);        // d2
                float p_ = g1p[t] * vuw[t];
                p_ += __shfl_xor(p_, 1, 64); p_ += __shfl_xor(p_, 2, 64); p_ += __shfl_xor(p_, 4, 64);
                if ((l & 7) == 0) atomicAdd(&scp[4], p_);        // s_uwg1 / SIG2
                vw0[t] = 0.f;
            }
            #pragma unroll
            for (int j4 = 0; j4 < 8; ++j4) {
                const float4 dd = *(const float4*)&vt2[cb + 4*j4];
                Areg[4*j4]   += cr*dd.x; Areg[4*j4+1] += cr*dd.y;
                Areg[4*j4+2] += cr*dd.z; Areg[4*j4+3] += cr*dd.w;
            }
            // write-through A^T
            #pragma unroll
            for (int j = 0; j < 32; ++j) At[(cb + j)*LDT + r] = Areg[j];
            // fused next-step az = A_new z_next (z prefetched in Pb)
            if (e + 1 < EE) {
                float s2 = 0.f;
                #pragma unroll
                for (int j4 = 0; j4 < 8; ++j4) {
                    const float4 x = *(const float4*)&vz[cb + 4*j4];
                    s2 += Areg[4*j4]*x.x + Areg[4*j4+1]*x.y + Areg[4*j4+2]*x.z + Areg[4*j4+3]*x.w;
                }
                atomicAdd(&vaz[r], s2);
            }
        }
        __syncthreads();
    }

    // epilogue: post_mean from Areg
    {
        float* dst = out + (size_t)b*(MM*CC) + r*CC + cb;
        #pragma unroll
        for (int j4 = 0; j4 < 8; ++j4) {
            float4 v; v.x = Areg[4*j4]; v.y = Areg[4*j4+1]; v.z = Areg[4*j4+2]; v.w = Areg[4*j4+3];
            *(float4*)&dst[4*j4] = v;
        }
    }
    // post_cov from Ureg + diag extraction (static indexing)
    float qd = 1.f;
    {
        float* dst = out + (size_t)BB*(MM*CC) + (size_t)b*(MM*MM) + r*MM + cb;
        #pragma unroll
        for (int j4 = 0; j4 < 8; ++j4) {
            float4 v; v.x = Ureg[4*j4]; v.y = Ureg[4*j4+1]; v.z = Ureg[4*j4+2]; v.w = Ureg[4*j4+3];
            *(float4*)&dst[4*j4] = v;
            if (cb + 4*j4     == r) qd = v.x;
            if (cb + 4*j4 + 1 == r) qd = v.y;
            if (cb + 4*j4 + 2 == r) qd = v.z;
            if (cb + 4*j4 + 3 == r) qd = v.w;
        }
    }
    // dkl = mean_b[ C*sum(q/p) + sum((A-A0)^2)/p - C*M + C*sum(log p - log q) ]
    {
        const float inv_p = 1.0f / pvar;
        float acc = 0.f;
        const float* src = mean0 + r*CC + cb;
        #pragma unroll
        for (int j4 = 0; j4 < 8; ++j4) {
            const float4 a0 = *(const float4*)&src[4*j4];
            const float dx = Areg[4*j4]   - a0.x, dy = Areg[4*j4+1] - a0.y;
            const float dz = Areg[4*j4+2] - a0.z, dw = Areg[4*j4+3] - a0.w;
            acc += dx*dx + dy*dy + dz*dz + dw*dw;
        }
        float local = acc * inv_p;
        if (q == (r >> 5))   // owner of diagonal element of row r
            local += (float)CC * (qd*inv_p + logf(pvar) - logf(qd));
        #pragma unroll
        for (int m2 = 1; m2 < 64; m2 <<= 1) local += __shfl_xor(local, m2, 64);
        if (l == 0) scal[16 + w] = local;
        __syncthreads();
        if (t == 0) {
            float tot = 0.f;
            #pragma unroll
            for (int i = 0; i < 8; ++i) tot += scal[16 + i];
            tot -= (float)(CC*MM);
            atomicAdd(out + (size_t)2*BB*MM*CC, tot * (1.0f/(float)BB));
        }
    }
}

extern "C" void kernel_launch(void* const* d_in, const int* in_sizes, int n_in,
                              void* d_out, int out_size, void* d_ws, size_t ws_size,
                              hipStream_t stream) {
    (void)in_sizes; (void)n_in; (void)out_size;
    const float* zin   = (const float*)d_in[0];
    const float* mean0 = (const float*)d_in[1];
    const float* lvar  = (const float*)d_in[2];
    float* out = (float*)d_out;
    float* dkl = out + (size_t)2*BB*MM*CC;
    const int use_ws = (d_ws != nullptr && ws_size >= (size_t)MM*MM*4) ? 1 : 0;
    float* ginv0 = (float*)d_ws;

    hipFuncSetAttribute((const void*)gpm_setup, hipFuncAttributeMaxDynamicSharedMemorySize, SMEM_BYTES);
    hipFuncSetAttribute((const void*)gpm_main,  hipFuncAttributeMaxDynamicSharedMemorySize, SMEM_BYTES);

    hipMemsetAsync(dkl, 0, sizeof(float), stream);
    if (use_ws)
        gpm_setup<<<1, 512, SMEM_BYTES, stream>>>(mean0, ginv0);
    gpm_main<<<BB, 512, SMEM_BYTES, stream>>>(zin, mean0, lvar, out, ginv0, use_ws);
}